// Round 1
// baseline (376.671 us; speedup 1.0000x reference)
//
#include <hip/hip_runtime.h>
#include <hip/hip_bf16.h>

#define IN_DIM 1024
#define OUT_DIM 1024
#define NE 8
#define NT 8192
#define KE (NE*IN_DIM)      // 8192
#define KPAD 64
#define KTOT (KE+KPAD)      // 8256
#define BM 128
#define BN 128
#define BK 64
#define NKT (KTOT/BK)       // 129

typedef unsigned short u16;
typedef __attribute__((ext_vector_type(4))) float f32x4;
typedef __attribute__((ext_vector_type(8))) short short8;

__device__ inline u16 f2bf(float f){
  unsigned u = __float_as_uint(f);
  return (u16)((u + 0x7fffu + ((u>>16)&1u)) >> 16);   // RNE
}

__device__ inline void gload16(const void* g, void* l){
  __builtin_amdgcn_global_load_lds(
    (const __attribute__((address_space(1))) void*)g,
    (__attribute__((address_space(3))) void*)l, 16, 0, 0);
}

// ---- gates = softmax(x @ Wg + bg), one wave per token, fp32 ----
__global__ void k_gates(const float* __restrict__ x, const float* __restrict__ Wg,
                        const float* __restrict__ bg, float* __restrict__ gates){
  int lane = threadIdx.x & 63;
  int n = blockIdx.x*4 + (threadIdx.x>>6);
  const float* xr = x + (size_t)n*IN_DIM;
  float p[NE];
  #pragma unroll
  for(int e=0;e<NE;e++) p[e]=0.f;
  for(int i = lane*4; i < IN_DIM; i += 256){
    float4 xv = *(const float4*)(xr + i);
    const float* wr = Wg + (size_t)i*NE;
    #pragma unroll
    for(int j=0;j<4;j++){
      float xs = (&xv.x)[j];
      #pragma unroll
      for(int e=0;e<NE;e++) p[e] = fmaf(xs, wr[j*NE+e], p[e]);
    }
  }
  #pragma unroll
  for(int e=0;e<NE;e++){
    float v = p[e];
    #pragma unroll
    for(int off=32;off;off>>=1) v += __shfl_xor(v, off);
    p[e]=v;
  }
  float m = -1e30f;
  #pragma unroll
  for(int e=0;e<NE;e++){ p[e] += bg[e]; m = fmaxf(m, p[e]); }
  float s = 0.f;
  #pragma unroll
  for(int e=0;e<NE;e++){ p[e] = __expf(p[e]-m); s += p[e]; }
  float inv = 1.f/s;
  if (lane < NE) gates[(size_t)n*NE + lane] = p[lane]*inv;
}

// ---- We [8192k][1024o] fp32 -> WeT bf16 [1024o][8256k] (transpose + cvt) ----
__global__ void k_wet(const float* __restrict__ We, u16* __restrict__ WeT){
  __shared__ float tile[64][65];
  int kb = blockIdx.x & 127;
  int ob = blockIdx.x >> 7;
  int k0 = kb*64, o0 = ob*64;
  int tr = threadIdx.x >> 4;        // 0..15
  int tc = (threadIdx.x & 15) * 4;
  #pragma unroll
  for (int p=0;p<4;p++){
    int r = p*16 + tr;
    float4 v = *(const float4*)(We + (size_t)(k0+r)*OUT_DIM + o0 + tc);
    tile[r][tc+0]=v.x; tile[r][tc+1]=v.y; tile[r][tc+2]=v.z; tile[r][tc+3]=v.w;
  }
  __syncthreads();
  #pragma unroll
  for (int p=0;p<4;p++){
    int r = p*16 + tr;              // o_local
    ushort4 o;
    o.x = f2bf(tile[tc+0][r]);
    o.y = f2bf(tile[tc+1][r]);
    o.z = f2bf(tile[tc+2][r]);
    o.w = f2bf(tile[tc+3][r]);
    *(ushort4*)(WeT + (size_t)(o0+r)*KTOT + k0 + tc) = o;
  }
}

// ---- bias tail: WeT[o][8192+e] = be[e][o]; [o][8200..8255] = 0 ----
__global__ void k_tail(const float* __restrict__ be, u16* __restrict__ WeT){
  int idx = blockIdx.x*256 + threadIdx.x;     // < 1024*64
  int o = idx >> 6, c = idx & 63;
  u16 v = 0;
  if (c < NE) v = f2bf(be[(size_t)c*OUT_DIM + o]);
  WeT[(size_t)o*KTOT + KE + c] = v;
}

// ---- A'[n][e*1024+k] = bf16(g[n,e]*x[n,k]); A'[n][8192+e]=g; pad 0 ----
__global__ void k_build_a(const float* __restrict__ x, const float* __restrict__ gates,
                          u16* __restrict__ Ap){
  int n = blockIdx.x*2 + (threadIdx.x>>7);
  int c = threadIdx.x & 127;
  int k0 = c*8;
  const float* xr = x + (size_t)n*IN_DIM;
  float4 v0 = *(const float4*)(xr+k0);
  float4 v1 = *(const float4*)(xr+k0+4);
  const float* grow = gates + (size_t)n*NE;
  u16* arow = Ap + (size_t)n*KTOT;
  #pragma unroll
  for(int e=0;e<NE;e++){
    float ge = grow[e];
    union { u16 u[8]; short8 v; } t;
    t.u[0]=f2bf(ge*v0.x); t.u[1]=f2bf(ge*v0.y); t.u[2]=f2bf(ge*v0.z); t.u[3]=f2bf(ge*v0.w);
    t.u[4]=f2bf(ge*v1.x); t.u[5]=f2bf(ge*v1.y); t.u[6]=f2bf(ge*v1.z); t.u[7]=f2bf(ge*v1.w);
    *(short8*)(arow + (size_t)e*IN_DIM + k0) = t.v;
  }
  if (c < KPAD){
    u16 tv = (c < NE) ? f2bf(grow[c]) : (u16)0;
    arow[KE + c] = tv;
  }
}

// ---- GEMM: C[8192x1024] = A'[8192x8256] @ WeT^T, bf16 MFMA 16x16x32 ----
// m97 structure: 128x128 tile, BK=64, 4 waves (64x64 each), global_load_lds 16B,
// XOR-swizzled LDS (granule' = granule ^ (row&7)): linear LDS dest, inverse-
// swizzled global source, swizzled ds_read_b128 -> conflict-free frag reads.
__global__ __launch_bounds__(256) void k_gemm(const u16* __restrict__ Ap,
      const u16* __restrict__ Wt, float* __restrict__ C){
  __shared__ u16 sA[BM*BK];
  __shared__ u16 sB[BN*BK];
  int tid = threadIdx.x;
  int wave = tid>>6, lane = tid&63;
  // XCD swizzle: 512 blocks, 8 XCDs -> each XCD owns one bn column (B panel L2-resident)
  int bid = blockIdx.x;
  int swz = (bid & 7)*(gridDim.x>>3) + (bid>>3);
  int bn = swz >> 6;      // 0..7
  int bm = swz & 63;      // 0..63
  int wr = wave>>1, wc = wave&1;

  const u16* pA[4]; const u16* pB[4];
  {
    int r_ = tid>>3, gl = tid&7;
    #pragma unroll
    for (int q=0;q<4;q++){
      int r = r_ + q*32;
      int sk = (gl ^ (r&7))<<3;     // inverse-swizzled source granule
      pA[q] = Ap + (size_t)(bm*BM + r)*KTOT + sk;
      pB[q] = Wt + (size_t)(bn*BN + r)*KTOT + sk;
    }
  }
  char* sAb = (char*)sA + wave*1024;
  char* sBb = (char*)sB + wave*1024;

  f32x4 acc[4][4];
  #pragma unroll
  for(int m=0;m<4;m++)
    #pragma unroll
    for(int n=0;n<4;n++)
      acc[m][n] = (f32x4){0.f,0.f,0.f,0.f};

  for (int kt=0; kt<NKT; ++kt){
    __syncthreads();                 // prev compute done before overwrite
    #pragma unroll
    for (int q=0;q<4;q++){
      gload16(pA[q], sAb + q*4096);
      gload16(pB[q], sBb + q*4096);
      pA[q] += BK; pB[q] += BK;
    }
    __syncthreads();                 // compiler drains vmcnt(0) before barrier
    int rA = wr*64 + (lane&15);
    int rB = wc*64 + (lane&15);
    int krow = lane>>4;
    #pragma unroll
    for (int kk=0; kk<BK; kk+=32){
      short8 af[4], bfr[4];
      int g0 = (kk>>3) + krow;
      #pragma unroll
      for (int m=0;m<4;m++){
        int R = rA + m*16;
        af[m] = *(const short8*)(sA + R*BK + ((g0 ^ (R&7))<<3));
      }
      #pragma unroll
      for (int n=0;n<4;n++){
        int R = rB + n*16;
        bfr[n] = *(const short8*)(sB + R*BK + ((g0 ^ (R&7))<<3));
      }
      #pragma unroll
      for (int m=0;m<4;m++)
        #pragma unroll
        for (int n=0;n<4;n++)
          acc[m][n] = __builtin_amdgcn_mfma_f32_16x16x32_bf16(af[m], bfr[n], acc[m][n], 0,0,0);
    }
  }
  // epilogue: C/D layout col=lane&15, row=(lane>>4)*4+reg (verified m89/m91)
  int row0 = bm*BM + wr*64 + (lane>>4)*4;
  int col0 = bn*BN + wc*64 + (lane&15);
  #pragma unroll
  for (int m=0;m<4;m++)
    #pragma unroll
    for (int n=0;n<4;n++)
      #pragma unroll
      for (int j=0;j<4;j++)
        C[(size_t)(row0 + m*16 + j)*OUT_DIM + col0 + n*16] = acc[m][n][j];
}

extern "C" void kernel_launch(void* const* d_in, const int* in_sizes, int n_in,
                              void* d_out, int out_size, void* d_ws, size_t ws_size,
                              hipStream_t stream){
  const float* x  = (const float*)d_in[0];
  const float* We = (const float*)d_in[1];
  const float* be = (const float*)d_in[2];
  const float* Wg = (const float*)d_in[3];
  const float* bg = (const float*)d_in[4];
  float* out = (float*)d_out;
  char* ws = (char*)d_ws;
  // ws layout: gates fp32 [8192][8] (256KB) | WeT bf16 [1024][8256] (16.9MB)
  //            | A' bf16 [8192][8256] (135.3MB)  -> total ~152.4MB
  float* gates = (float*)ws;
  u16* WeT = (u16*)(ws + 262144);
  u16* Ap  = (u16*)(ws + 262144 + (size_t)OUT_DIM*KTOT*2);

  k_gates  <<<NT/4, 256, 0, stream>>>(x, Wg, bg, gates);
  k_wet    <<<(KE/64)*(OUT_DIM/64), 256, 0, stream>>>(We, WeT);
  k_tail   <<<OUT_DIM*KPAD/256, 256, 0, stream>>>(be, WeT);
  k_build_a<<<NT/2, 256, 0, stream>>>(x, gates, Ap);
  k_gemm   <<<(NT/BM)*(OUT_DIM/BN), 256, 0, stream>>>(Ap, WeT, out);
}